// Round 6
// baseline (1042.865 us; speedup 1.0000x reference)
//
#include <hip/hip_runtime.h>
#include <cstdint>

// Problem constants
constexpr int Cc = 95;    // input channels
constexpr int Hh = 128;   // hidden
constexpr int G  = 512;   // 4*H gates
constexpr int Bb = 256;   // batch
constexpr int Tt = 1000;  // timesteps
#define EPSBN 1e-5f

typedef _Float16 half2v __attribute__((ext_vector_type(2)));
typedef _Float16 half8  __attribute__((ext_vector_type(8)));
typedef float floatx4 __attribute__((ext_vector_type(4)));
typedef float float4u __attribute__((ext_vector_type(4), aligned(4)));
typedef float float2u __attribute__((ext_vector_type(2), aligned(4)));

__device__ __forceinline__ unsigned pku(float a, float b) {
  return __builtin_bit_cast(unsigned, __builtin_amdgcn_cvt_pkrtz(a, b));
}
__device__ __forceinline__ float fsigm(float y) {
  y = fminf(30.f, fmaxf(-30.f, y));
  float e = __expf(-y);
  return __fdividef(1.f, 1.f + e);
}
__device__ __forceinline__ float ftanh2(float x) {  // tanh via exp(2x)
  float y = fminf(30.f, fmaxf(-30.f, 2.f * x));
  float e = __expf(y);
  return __fdividef(e - 1.f, e + 1.f);
}

// ---------------------------------------------------------------------------
// K0 (once per launch): fold BN into W_ih -> Wp f16 [512][96] (k=95 padded 0),
// bias'[g] = b_ih+b_hh + sum_c sft_c * W_ih[g][c].
// ---------------------------------------------------------------------------
__global__ __launch_bounds__(512)
void k0_prep(const float* __restrict__ gamma, const float* __restrict__ beta,
             const float* __restrict__ rmean, const float* __restrict__ rvar,
             const float* __restrict__ W_ih, const float* __restrict__ b_ih,
             const float* __restrict__ b_hh, float* __restrict__ biasp,
             _Float16* __restrict__ Wp) {
  __shared__ float scl[Cc], sft[Cc];
  const int t = threadIdx.x;
  if (t < Cc) {
    float s = gamma[t] * rsqrtf(rvar[t] + EPSBN);
    scl[t] = s;
    sft[t] = beta[t] - rmean[t] * s;
  }
  __syncthreads();
  float acc = b_ih[t] + b_hh[t];
  const float* wr = W_ih + (size_t)t * Cc;
  for (int c = 0; c < Cc; ++c) {
    float w = wr[c];
    acc = fmaf(sft[c], w, acc);
    Wp[t * 96 + c] = (_Float16)(w * scl[c]);  // RNE cast
  }
  Wp[t * 96 + 95] = (_Float16)0.f;
  biasp[t] = acc;
}

// ---------------------------------------------------------------------------
// K1: xw = x_f16 . Wp^T + bias'  via mfma_f32_16x16x32_f16 (proven r5).
// ---------------------------------------------------------------------------
template <int TC>
__global__ __launch_bounds__(512)
void k1_mfma(const float* __restrict__ x, const _Float16* __restrict__ Wp,
             const float* __restrict__ biasp, float* __restrict__ xw, int t0) {
  const int tid = threadIdx.x;
  const int wave = tid >> 6, lane = tid & 63;
  const int wm = wave >> 2, wn = wave & 3;
  const int row0 = blockIdx.x * 64 + wm * 32;
  const int nb0 = wn * 128;
  const int l15 = lane & 15, lg = lane >> 4;

  uint4 afr[2][3];
#pragma unroll
  for (int mt = 0; mt < 2; ++mt) {
    int m = row0 + mt * 16 + l15;
    int b = m / TC, tl = m - b * TC;
    const float* xr = x + ((size_t)b * Tt + t0 + tl) * Cc;
#pragma unroll
    for (int kk = 0; kk < 3; ++kk) {
      int k = kk * 32 + lg * 8;
      float4u p0 = *reinterpret_cast<const float4u*>(xr + k);
      float e4, e5, e6, e7;
      if (k == 88) {
        float2u q = *reinterpret_cast<const float2u*>(xr + 92);
        e4 = q[0]; e5 = q[1]; e6 = xr[94]; e7 = 0.f;
      } else {
        float4u p1 = *reinterpret_cast<const float4u*>(xr + k + 4);
        e4 = p1[0]; e5 = p1[1]; e6 = p1[2]; e7 = p1[3];
      }
      afr[mt][kk] = make_uint4(pku(p0[0], p0[1]), pku(p0[2], p0[3]),
                               pku(e4, e5), pku(e6, e7));
    }
  }

  floatx4 acc[2][8] = {};
#pragma unroll
  for (int nt = 0; nt < 8; ++nt) {
    const _Float16* wrow = Wp + (size_t)(nb0 + nt * 16 + l15) * 96 + lg * 8;
#pragma unroll
    for (int kk = 0; kk < 3; ++kk) {
      uint4 bfr = *reinterpret_cast<const uint4*>(wrow + kk * 32);
      half8 bv = __builtin_bit_cast(half8, bfr);
      acc[0][nt] = __builtin_amdgcn_mfma_f32_16x16x32_f16(
          __builtin_bit_cast(half8, afr[0][kk]), bv, acc[0][nt], 0, 0, 0);
      acc[1][nt] = __builtin_amdgcn_mfma_f32_16x16x32_f16(
          __builtin_bit_cast(half8, afr[1][kk]), bv, acc[1][nt], 0, 0, 0);
    }
  }

#pragma unroll
  for (int nt = 0; nt < 8; ++nt) {
    int n = nb0 + nt * 16 + l15;
    float bias = biasp[n];
#pragma unroll
    for (int mt = 0; mt < 2; ++mt) {
      int rbase = row0 + mt * 16 + lg * 4;
#pragma unroll
      for (int r = 0; r < 4; ++r)
        xw[(size_t)(rbase + r) * G + n] = acc[mt][nt][r] + bias;
    }
  }
}

// ---------------------------------------------------------------------------
// K2: per-batch LSTM recurrence via MFMA. 256 blocks x 256 threads (4 waves).
// Wave w owns units [32w, 32w+32): 8 A-tiles (4 gates x 2 halves) of W_hh
// rows, f16, persistent in 128 VGPRs. Per step:
//   B-frags: 4x ds_read_b128 of f16 h (broadcast; B[k][n]=h[k], n wasted)
//   32 MFMA 16x16x32 -> all 128 gate rows of this wave's units
//   gates -> wave-private LDS slice (no barrier: same-wave DS ordering)
//   each lane: full i/f/g/o -> c,h update for unit u = lane&31 (x2 redundant)
//   h -> f16 LDS (double-buffered), ONE barrier per step.
// ---------------------------------------------------------------------------
template <int TC>
__global__ __launch_bounds__(256, 1)
void k2_lstm(const float* __restrict__ xw, const float* __restrict__ W_hh,
             float* __restrict__ hstate, float* __restrict__ cstate,
             const float* __restrict__ fc_w, const float* __restrict__ fc_b,
             float* __restrict__ out, int t0) {
  __shared__ __align__(16) _Float16 h2[2][Hh];  // f16 h, double-buffered
  __shared__ __align__(16) float gl[G];         // gate scratch (wave-private slices)
  __shared__ float h32[Hh];

  const int b = blockIdx.x;
  const int tid = threadIdx.x;
  const int w = tid >> 6, lane = tid & 63;
  const int l15 = lane & 15, lg = lane >> 4;
  const int u = lane & 31;        // unit within wave (lanes 32+ duplicate)
  const int uj = 32 * w + u;      // global unit

  // A-fragments: W_hh rows (f16) for 8 tiles x 4 k-chunks -> 128 VGPRs.
  uint4 afr[8][4];
#pragma unroll
  for (int q = 0; q < 4; ++q)
#pragma unroll
    for (int hh = 0; hh < 2; ++hh) {
      const float* wr =
          W_hh + (size_t)(q * 128 + 32 * w + 16 * hh + l15) * Hh + 8 * lg;
#pragma unroll
      for (int kc = 0; kc < 4; ++kc) {
        float4u p0 = *reinterpret_cast<const float4u*>(wr + 32 * kc);
        float4u p1 = *reinterpret_cast<const float4u*>(wr + 32 * kc + 4);
        afr[2 * q + hh][kc] = make_uint4(pku(p0[0], p0[1]), pku(p0[2], p0[3]),
                                         pku(p1[0], p1[1]), pku(p1[2], p1[3]));
      }
    }

  // init h (f16 LDS) and c (register, redundant in both half-waves)
  float creg = 0.f, hreg = 0.f;
  if (t0 == 0) {
    if (tid < Hh / 2)
      reinterpret_cast<unsigned*>(h2[0])[tid] = 0u;
  } else {
    creg = cstate[b * Hh + uj];
    hreg = hstate[b * Hh + uj];
    if (tid < Hh / 2)
      reinterpret_cast<unsigned*>(h2[0])[tid] =
          pku(hstate[b * Hh + 2 * tid], hstate[b * Hh + 2 * tid + 1]);
  }
  __syncthreads();

  const float* xwb = xw + (size_t)b * TC * G;
  float cur0 = xwb[0 * 128 + uj], cur1 = xwb[1 * 128 + uj];
  float cur2 = xwb[2 * 128 + uj], cur3 = xwb[3 * 128 + uj];
  float nxt0 = 0.f, nxt1 = 0.f, nxt2 = 0.f, nxt3 = 0.f;
  if (TC > 1) {
    nxt0 = xwb[G + 0 * 128 + uj]; nxt1 = xwb[G + 1 * 128 + uj];
    nxt2 = xwb[G + 2 * 128 + uj]; nxt3 = xwb[G + 3 * 128 + uj];
  }

  for (int tl = 0; tl < TC; ++tl) {
    const int rb = tl & 1;
    float pre0 = 0.f, pre1 = 0.f, pre2 = 0.f, pre3 = 0.f;
    if (tl + 2 < TC) {
      const float* xp = xwb + (size_t)(tl + 2) * G;
      pre0 = xp[0 * 128 + uj]; pre1 = xp[1 * 128 + uj];
      pre2 = xp[2 * 128 + uj]; pre3 = xp[3 * 128 + uj];
    }

    // B-fragments from f16 h (address depends on lg only -> broadcast read)
    uint4 bfr[4];
#pragma unroll
    for (int kc = 0; kc < 4; ++kc)
      bfr[kc] = *reinterpret_cast<const uint4*>(&h2[rb][32 * kc + 8 * lg]);

    floatx4 acc[8] = {};
#pragma unroll
    for (int t = 0; t < 8; ++t)
#pragma unroll
      for (int kc = 0; kc < 4; ++kc)
        acc[t] = __builtin_amdgcn_mfma_f32_16x16x32_f16(
            __builtin_bit_cast(half8, afr[t][kc]),
            __builtin_bit_cast(half8, bfr[kc]), acc[t], 0, 0, 0);

    // gates -> wave-private LDS slice (cols 0 of D; no barrier needed)
    if (l15 == 0) {
#pragma unroll
      for (int q = 0; q < 4; ++q)
#pragma unroll
        for (int hh = 0; hh < 2; ++hh)
          *reinterpret_cast<floatx4*>(
              &gl[q * 128 + 32 * w + 16 * hh + 4 * lg]) = acc[2 * q + hh];
    }
    // read back own unit's 4 gates (same-wave DS ordering; conflict-free)
    float gi = gl[0 * 128 + uj] + cur0;
    float gf = gl[1 * 128 + uj] + cur1;
    float gg = gl[2 * 128 + uj] + cur2;
    float go = gl[3 * 128 + uj] + cur3;

    float i_ = fsigm(gi);
    float f_ = fsigm(gf);
    float g_ = ftanh2(gg);   // tanh(x) via exp(2x)
    float o_ = fsigm(go);

    creg = fmaf(f_, creg, i_ * g_);
    hreg = o_ * ftanh2(creg);

    // pack (h_u, h_{u+1}) -> next h buffer; 16 writers per wave
    float hn = __shfl_down(hreg, 1);
    if (lane < 32 && !(u & 1))
      reinterpret_cast<unsigned*>(h2[rb ^ 1])[uj >> 1] = pku(hreg, hn);
    __syncthreads();

    cur0 = nxt0; cur1 = nxt1; cur2 = nxt2; cur3 = nxt3;
    nxt0 = pre0; nxt1 = pre1; nxt2 = pre2; nxt3 = pre3;
  }

  if (lane < 32) {
    hstate[b * Hh + uj] = hreg;
    cstate[b * Hh + uj] = creg;
    h32[uj] = hreg;
  }
  __syncthreads();

  if (t0 + TC == Tt && tid < 4) {
    float s = fc_b[tid];
    for (int jj = 0; jj < Hh; ++jj) s = fmaf(h32[jj], fc_w[tid * Hh + jj], s);
    out[b * 4 + tid] = s;
  }
}

// ---------------------------------------------------------------------------
template <int TC>
static void run_chunks(const float* x, const float* gamma, const float* beta,
                       const float* rmean, const float* rvar,
                       const float* W_ih, const float* W_hh,
                       const float* b_ih, const float* b_hh,
                       const float* fc_w, const float* fc_b, float* out,
                       void* d_ws, hipStream_t stream) {
  char* ws = reinterpret_cast<char*>(d_ws);
  float* xwp  = reinterpret_cast<float*>(ws);
  size_t off  = (size_t)Bb * TC * G * 4;
  float* hst  = reinterpret_cast<float*>(ws + off);  off += (size_t)Bb * Hh * 4;
  float* cst  = reinterpret_cast<float*>(ws + off);  off += (size_t)Bb * Hh * 4;
  float* bia  = reinterpret_cast<float*>(ws + off);  off += 512 * 4;
  off = (off + 15) & ~(size_t)15;
  _Float16* Wp = reinterpret_cast<_Float16*>(ws + off);

  k0_prep<<<dim3(1), dim3(512), 0, stream>>>(gamma, beta, rmean, rvar, W_ih,
                                             b_ih, b_hh, bia, Wp);
  for (int t0 = 0; t0 < Tt; t0 += TC) {
    k1_mfma<TC><<<dim3(Bb * TC / 64), dim3(512), 0, stream>>>(x, Wp, bia, xwp,
                                                              t0);
    k2_lstm<TC><<<dim3(Bb), dim3(256), 0, stream>>>(xwp, W_hh, hst, cst, fc_w,
                                                    fc_b, out, t0);
  }
}

extern "C" void kernel_launch(void* const* d_in, const int* in_sizes, int n_in,
                              void* d_out, int out_size, void* d_ws,
                              size_t ws_size, hipStream_t stream) {
  const float* x     = (const float*)d_in[0];
  const float* gamma = (const float*)d_in[1];
  const float* beta  = (const float*)d_in[2];
  const float* rmean = (const float*)d_in[3];
  const float* rvar  = (const float*)d_in[4];
  const float* W_ih  = (const float*)d_in[5];
  const float* W_hh  = (const float*)d_in[6];
  const float* b_ih  = (const float*)d_in[7];
  const float* b_hh  = (const float*)d_in[8];
  const float* fc_w  = (const float*)d_in[9];
  const float* fc_b  = (const float*)d_in[10];
  float* out = (float*)d_out;

  auto need = [](int tc) {
    return (size_t)Bb * tc * G * 4 + 2 * (size_t)Bb * Hh * 4 + 512 * 4 + 16 +
           (size_t)512 * 96 * 2;
  };

  if (ws_size >= need(250)) {
    run_chunks<250>(x, gamma, beta, rmean, rvar, W_ih, W_hh, b_ih, b_hh, fc_w,
                    fc_b, out, d_ws, stream);
  } else if (ws_size >= need(125)) {
    run_chunks<125>(x, gamma, beta, rmean, rvar, W_ih, W_hh, b_ih, b_hh, fc_w,
                    fc_b, out, d_ws, stream);
  } else if (ws_size >= need(50)) {
    run_chunks<50>(x, gamma, beta, rmean, rvar, W_ih, W_hh, b_ih, b_hh, fc_w,
                   fc_b, out, d_ws, stream);
  } else {
    run_chunks<10>(x, gamma, beta, rmean, rvar, W_ih, W_hh, b_ih, b_hh, fc_w,
                   fc_b, out, d_ws, stream);
  }
}